// Round 7
// baseline (191.759 us; speedup 1.0000x reference)
//
#include <hip/hip_runtime.h>
#include <math.h>

#define N_VOX (96*96*96)        // 884736 voxels per volume
#define NVOL 8                  // 4 pred + 4 target volumes
#define NEL (4*N_VOX)           // 3538944 elements in pred/target
#define PLANE (96*96)           // 9216

// tile geometry for local CCL: full d-span x TW x TH
// (TH=4: 2304 blocks -> 8 blocks/CU wave-slot-capped residency; round-5
//  lesson: 144x8 tiles gave only 4.5 blocks/CU -> 40% occupancy, latency-bound)
#define TW 8
#define TH 4
#define TILES_W 12
#define TILES_H 24
#define TILE_VOX (96*TW*TH)     // 3072
#define TILE_WORDS (TILE_VOX/32) // 96

#define NBW 11                  // interior tile boundaries, w axis
#define NBH 23                  // interior tile boundaries, h axis
#define NPLANES (NBW+NBH)       // 34 boundary plane-pairs per volume
#define FACES_PER_VOL (2*NPLANES*PLANE) // 626688 ushorts
#define MAXR 40192              // dense roots that fit in 157 KB LDS
#define FALLR 65536             // global fallback capacity (ushort ID space)
#define SEGCAP 4608             // hard bound: <=48 starts/line * 96 lines/plane
#define HT2N 4096               // per-plane dedup hash entries (16 KB LDS)
#define MAX_PROBES 16

// workspace header layout (4 KB, zeroed once). Per-volume counters are
// strided to 128 B so 8 volumes never share a cache line (round-4 lesson:
// same-line cross-XCD atomics serialize at ~5 ns each).
#define WS_ACC   0
#define WS_ROOT  256            // int, volume v at int-index (v<<5)
#define WS_EVT   1536           // int, volume v at int-index (v<<5)
#define WS_PCNT  2816           // int [v*NPLANES + f], single writer each
#define WS_HDR   4096

// ---------------------------------------------------------------------------
// generic-pointer union-find (works on LDS or global array). Labels only
// decrease (atomicMin) -> monotone, no cycles.
__device__ __forceinline__ int uf_find(int* __restrict__ L, int x) {
    int r = x;
    int p = L[r];
    while (p != r) { r = p; p = L[r]; }
    if (r != x) atomicMin(&L[x], r);     // path compression (monotone-safe)
    return r;
}

// returns # destroyed self-loops (exact union events).
__device__ __forceinline__ int uf_merge(int* __restrict__ L, int l1, int l2) {
    int ev = 0;
    while (l1 != l2) {
        if (l1 < l2) { int t = l1; l1 = l2; l2 = t; }   // l1 > l2
        int l3 = atomicMin(&L[l1], l2);
        if (l3 == l1) { ev++; l1 = l2; }
        else l1 = l3;
    }
    return ev;
}

// merge on LDS tile labels (links only run-start slots)
__device__ __forceinline__ void merge_local(int* lab, int l1, int l2) {
    while (l1 != l2 && l1 != lab[l1]) l1 = lab[l1];
    while (l1 != l2 && l2 != lab[l2]) l2 = lab[l2];
    while (l1 != l2) {
        if (l1 < l2) { int t = l1; l1 = l2; l2 = t; }
        int l3 = atomicMin(&lab[l1], l2);
        l1 = (l3 == l1) ? l2 : l3;
    }
}

// start index of the consecutive-fg d-run containing fg voxel i (d = i%96).
__device__ __forceinline__ int run_start(const unsigned* fm, int i, int d) {
    int rowb = (i - d) >> 5;
    int k = d >> 5, bit = d & 31;
    unsigned below = bit ? (~fm[rowb + k] & ((1u << bit) - 1)) : 0u;
    int z = -1;
    if (below) z = (k << 5) + 31 - __builtin_clz(below);
    else if (k > 0) {
        unsigned n1 = ~fm[rowb + k - 1];
        if (n1) z = ((k - 1) << 5) + 31 - __builtin_clz(n1);
        else if (k > 1) {
            unsigned n0 = ~fm[rowb];
            if (n0) z = 31 - __builtin_clz(n0);
        }
    }
    return (i - d) + z + 1;
}

// ---------------------------------------------------------------------------
// Phase 1: run-based per-tile CCL in LDS. Roots get DENSE per-volume IDs
// (block base via one atomicAdd on rootcnt[v] + intra-block wave scan).
// Outputs ONLY compact ushort face arrays + rootcnt + focal partial.
__global__ __launch_bounds__(256) void ccl_local(const float* __restrict__ pred,
                                                 const float* __restrict__ targ,
                                                 unsigned short* __restrict__ faces,
                                                 int* __restrict__ rootcnt,
                                                 float* __restrict__ acc,
                                                 int vbase) {
    __shared__ int lab[TILE_VOX];            // 12 KB
    __shared__ unsigned fm[TILE_WORDS];      // 384 B fg bit array
    __shared__ float fws[4];
    __shared__ int   iws[4];
    __shared__ int   gbase;

    int vloc = blockIdx.y;
    int v = vbase + vloc;
    int tile = blockIdx.x;                   // 0..287
    int tw = tile % TILES_W, th = tile / TILES_W;
    int w0 = tw * TW, h0 = th * TH;
    int tbase = h0 * PLANE + w0 * 96;        // global index of tile origin
    unsigned short* Fw = faces + (size_t)vloc * FACES_PER_VOL;  // [b][side][h*96+d]
    unsigned short* Fh = Fw + 2 * NBW * PLANE;                  // [b][side][w*96+d]

    // ---- load: fg bits via ballot; fast focal partial for pred volumes ----
    float fsum = 0.0f;
    for (int it = 0; it < TILE_VOX / 256; it++) {
        int i = it * 256 + threadIdx.x;
        int lh = i / 768;                    // i = lh*768 + lw*96 + d
        int j = tbase + i + lh * 8448;       // global voxel index (PLANE-768)
        bool f;
        if (v < 4) {
            float xv = pred[(size_t)v * N_VOX + j];
            float tv = targ[(size_t)v * N_VOX + j];
            f = xv > 0.0f;                   // sigmoid(x)>0.5 <=> x>0
            float m   = (tv == 1.0f) ? -xv : xv;
            float at  = (tv == 1.0f) ? 0.25f : 0.75f;
            float e   = __expf(-fabsf(m));
            float inv = 1.0f / (1.0f + e);
            float sig = inv * ((m >= 0.0f) ? 1.0f : e);    // sigmoid(m)
            float sp  = fmaxf(m, 0.0f) + __logf(1.0f + e); // softplus(m)
            fsum += at * sig * sig * sp;
        } else {
            f = targ[(size_t)(v - 4) * N_VOX + j] > 0.5f;
        }
        unsigned long long bal = __ballot(f);
        if ((threadIdx.x & 63) == 0) {
            fm[i >> 5]       = (unsigned)bal;
            fm[(i >> 5) + 1] = (unsigned)(bal >> 32);
        }
        lab[i] = i;
    }
    __syncthreads();

    // ---- merge: word-level overlap-segment starts, w then h direction ----
    // w-dir: lh<4 x lw-pairs(7) x k(3) = 84 items; h-dir: lh-pairs(3) x lw(8)
    // x k(3) = 72 items; total 156.
    for (int t = threadIdx.x; t < 156; t += 256) {
        bool wdir = t < 84;
        int tt = wdir ? t : t - 84;
        int lh, lw, k;
        if (wdir) { lh = tt / 21; int rem = tt % 21; lw = rem / 3; k = rem % 3; }
        else      { lh = tt / 24; int rem = tt % 24; lw = rem / 3; k = rem % 3; }
        int wb = (lh * 8 + lw) * 3 + k;
        int nb = wb + (wdir ? 3 : 24);
        unsigned ov = fm[wb] & fm[nb];
        if (!ov) continue;
        unsigned carry = (k > 0) ? ((fm[wb - 1] & fm[nb - 1]) >> 31) : 0u;
        unsigned starts = ov & ~((ov << 1) | carry);
        int base_i = wb << 5;
        int dir = wdir ? 96 : 768;
        while (starts) {
            int b = __builtin_ctz(starts);
            starts &= starts - 1;
            int i = base_i + b;
            int d = (k << 5) + b;
            merge_local(lab, run_start(fm, i, d), run_start(fm, i + dir, d));
        }
    }
    __syncthreads();

    // ---- R1: count tile roots (start slots with lab[i]==i) per thread ----
    int myroots = 0;
    for (int t = threadIdx.x; t < TILE_WORDS; t += 256) {
        unsigned m = fm[t];
        if (!m) continue;
        unsigned carry = (t % 3) ? (fm[t - 1] >> 31) : 0u;
        unsigned starts = m & ~((m << 1) | carry);
        int base_i = t << 5;
        while (starts) {
            int b = __builtin_ctz(starts); starts &= starts - 1;
            if (lab[base_i + b] == base_i + b) myroots++;
        }
    }
    // wave inclusive scan + cross-wave prefix + one atomicAdd for the base
    int s = myroots;
    for (int off = 1; off < 64; off <<= 1) {
        int tv2 = __shfl_up(s, off, 64);
        if ((threadIdx.x & 63) >= off) s += tv2;
    }
    int wid = threadIdx.x >> 6;
    if ((threadIdx.x & 63) == 63) iws[wid] = s;
    __syncthreads();
    int wbase = 0;
    for (int k = 0; k < wid; k++) wbase += iws[k];
    if (threadIdx.x == 0)
        gbase = atomicAdd(&rootcnt[v << 5], iws[0] + iws[1] + iws[2] + iws[3]);
    __syncthreads();
    int nid = gbase + wbase + (s - myroots);   // exclusive base for my roots

    // ---- R2: assign dense IDs to roots (each thread owns its words) ----
    for (int t = threadIdx.x; t < TILE_WORDS; t += 256) {
        unsigned m = fm[t];
        if (!m) continue;
        unsigned carry = (t % 3) ? (fm[t - 1] >> 31) : 0u;
        unsigned starts = m & ~((m << 1) | carry);
        int base_i = t << 5;
        while (starts) {
            int b = __builtin_ctz(starts); starts &= starts - 1;
            int i = base_i + b;
            if (lab[i] == i) lab[i] = ~(nid++);
        }
    }
    __syncthreads();

    // ---- R3: flatten non-root starts to ~denseID (chains end negative) ----
    for (int t = threadIdx.x; t < TILE_WORDS; t += 256) {
        unsigned m = fm[t];
        if (!m) continue;
        unsigned carry = (t % 3) ? (fm[t - 1] >> 31) : 0u;
        unsigned starts = m & ~((m << 1) | carry);
        int base_i = t << 5;
        while (starts) {
            int b = __builtin_ctz(starts); starts &= starts - 1;
            int i = base_i + b;
            int p = lab[i];
            if (p >= 0) {                    // non-root start
                int r = p, q2 = lab[r];
                while (q2 >= 0) { r = q2; q2 = lab[r]; }
                lab[i] = q2;                 // adopt finalized ~denseID
            }
        }
    }
    __syncthreads();

    // ---- resolve + store the 4 interior-adjacent faces (ushort4 groups) ----
    // f0: lw=0 (side B of w-boundary tw-1), 96 items (u=lh<4 x 24)
    // f1: lw=7 (side A of w-boundary tw),   96 items
    // f2: lh=0 (side B of h-boundary th-1), 192 items (u=lw<8 x 24)
    // f3: lh=3 (side A of h-boundary th),   192 items
    for (int t = threadIdx.x; t < 576; t += 256) {
        int i0 = -1, d4 = 0;
        unsigned short* dst = 0;
        if (t < 192) {
            int f = t / 96, g = t % 96;
            int u = g / 24;                  // u = lh
            d4 = (g % 24) * 4;
            if (f == 0) {
                if (tw == 0) continue;
                i0  = u * 768 + d4;
                dst = Fw + ((tw - 1) * 2 + 1) * PLANE + (h0 + u) * 96 + d4;
            } else {
                if (tw == TILES_W - 1) continue;
                i0  = u * 768 + 7 * 96 + d4;
                dst = Fw + (tw * 2) * PLANE + (h0 + u) * 96 + d4;
            }
        } else {
            int f = (t - 192) / 192, g = (t - 192) % 192;
            int u = g / 24;                  // u = lw
            d4 = (g % 24) * 4;
            if (f == 0) {
                if (th == 0) continue;
                i0  = u * 96 + d4;
                dst = Fh + ((th - 1) * 2 + 1) * PLANE + (w0 + u) * 96 + d4;
            } else {
                if (th == TILES_H - 1) continue;
                i0  = (TH - 1) * 768 + u * 96 + d4;
                dst = Fh + (th * 2) * PLANE + (w0 + u) * 96 + d4;
            }
        }
        unsigned mw = fm[i0 >> 5];           // bits d4..d4+3 in one word
        unsigned short vals[4];
        bool prevf = false;
        for (int q = 0; q < 4; q++) {
            bool fb = (mw >> ((d4 & 31) + q)) & 1;
            if (fb) vals[q] = prevf ? vals[q - 1]
                                    : (unsigned short)(~lab[run_start(fm, i0 + q, d4 + q)]);
            else vals[q] = 0xFFFFu;
            prevf = fb;
        }
        *(ushort4*)dst = make_ushort4(vals[0], vals[1], vals[2], vals[3]);
    }

    // ---- wave-shuffle reduction: focal partial ----
    for (int off = 32; off; off >>= 1) fsum += __shfl_down(fsum, off, 64);
    if ((threadIdx.x & 63) == 0) fws[wid] = fsum;
    __syncthreads();
    if (threadIdx.x == 0) {
        float ft = fws[0] + fws[1] + fws[2] + fws[3];
        if (v < 4 && ft != 0.0f) atomicAdd(acc, ft);
    }
}

// ---------------------------------------------------------------------------
// Phase 2a: WIDE pair extraction + dedup. One block per (plane-pair, volume).
// Streams its 2x9216-ushort plane coalesced, extracts overlap-segment-start
// (a,b) pairs, dedups via a private 16 KB LDS hash, writes uniques to its
// PRIVATE global segment indexed by an LDS counter -- zero global atomics
// (round-4 lesson). Plane-pair p offset = 2*p*PLANE (w planes then h planes,
// contiguous). Probe-cap dupes kept (harmless downstream).
__global__ __launch_bounds__(256) void ccl_pairs(const unsigned short* __restrict__ faces,
                                                 unsigned* __restrict__ pairs,
                                                 int* __restrict__ pcnt,
                                                 int vbase) {
    __shared__ unsigned ht[HT2N];            // 16 KB
    __shared__ int nloc;
    for (int i = threadIdx.x; i < HT2N; i += 256) ht[i] = 0xFFFFFFFFu;
    if (threadIdx.x == 0) nloc = 0;
    __syncthreads();

    int f    = blockIdx.x;                   // plane pair 0..33
    int vloc = blockIdx.y;
    int v    = vbase + vloc;
    const unsigned short* A = faces + (size_t)vloc * FACES_PER_VOL
                                    + (size_t)(2 * f) * PLANE;
    const unsigned short* B = A + PLANE;
    unsigned* pb = pairs + ((size_t)vloc * NPLANES + f) * SEGCAP;

    const int GPP = PLANE / 8;               // 1152 8-wide groups
    for (int g = threadIdx.x; g < GPP; g += 256) {
        int e8 = g * 8;
        int4 aw = *(const int4*)(A + e8);    // 8 ushorts, coalesced 16B
        int4 bw = *(const int4*)(B + e8);
        unsigned a32[4] = {(unsigned)aw.x, (unsigned)aw.y, (unsigned)aw.z, (unsigned)aw.w};
        unsigned b32[4] = {(unsigned)bw.x, (unsigned)bw.y, (unsigned)bw.z, (unsigned)bw.w};
        bool pf = false;
        if (e8 % 96) pf = (A[e8 - 1] != 0xFFFFu) && (B[e8 - 1] != 0xFFFFu);
        #pragma unroll
        for (int q = 0; q < 8; q++) {
            unsigned av = (a32[q >> 1] >> ((q & 1) * 16)) & 0xFFFFu;
            unsigned bv = (b32[q >> 1] >> ((q & 1) * 16)) & 0xFFFFu;
            bool f2 = (av != 0xFFFFu) && (bv != 0xFFFFu);
            if (f2 && !pf && av != bv) {     // overlap-segment start along d
                unsigned lo = av < bv ? av : bv;
                unsigned hi = av < bv ? bv : av;
                unsigned key = (lo << 16) | hi;
                unsigned h = (key * 2654435761u) >> 20;   // -> 12-bit slot
                bool fresh = false;
                for (int pr = 0; pr < MAX_PROBES; pr++) {
                    unsigned prev = atomicCAS(&ht[h], 0xFFFFFFFFu, key);
                    if (prev == 0xFFFFFFFFu) { fresh = true; break; }
                    if (prev == key) break;
                    h = (h + 1) & (HT2N - 1);
                    if (pr == MAX_PROBES - 1) fresh = true;  // cap: keep dupe
                }
                if (fresh) {
                    int ix = atomicAdd(&nloc, 1);    // LDS atomic, on-CU
                    pb[ix] = key;                    // ix < SEGCAP bound
                }
            }
            pf = f2;
        }
    }
    __syncthreads();
    if (threadIdx.x == 0) pcnt[v * NPLANES + f] = nloc;   // single writer
}

// ---------------------------------------------------------------------------
// Phase 2b: NARROW exact union-find. One 1024-thread block per volume over
// the dense root ID space in 157 KB LDS; walks the 34 per-plane unique-pair
// segments. components = roots - events (destroyed self-loops).
__global__ __launch_bounds__(1024) void ccl_union(const unsigned* __restrict__ pairs,
                                                  int* __restrict__ gfall,
                                                  const int* __restrict__ rootcnt,
                                                  const int* __restrict__ pcnt,
                                                  int* __restrict__ events,
                                                  int vbase) {
    __shared__ int slab[MAXR];               // 157 KB dense union-find
    __shared__ int wsum[16];
    int vloc = blockIdx.x;
    int v = vbase + vloc;
    int R  = rootcnt[v << 5];

    int* lab = (R <= MAXR) ? (int*)slab : (gfall + (size_t)vloc * FALLR);
    for (int i = threadIdx.x; i < R; i += 1024) lab[i] = i;
    __syncthreads();

    int ev = 0;
    for (int f = 0; f < NPLANES; f++) {
        int np = pcnt[v * NPLANES + f];
        const unsigned* pb = pairs + ((size_t)vloc * NPLANES + f) * SEGCAP;
        for (int i = threadIdx.x; i < np; i += 1024) {
            unsigned key = pb[i];
            int a = (int)(key >> 16), b = (int)(key & 0xFFFFu);
            int ra = uf_find(lab, a);
            int rb = uf_find(lab, b);
            if (ra != rb) ev += uf_merge(lab, ra, rb);
        }
    }

    // block reduction of union events
    for (int off = 32; off; off >>= 1) ev += __shfl_down(ev, off, 64);
    if ((threadIdx.x & 63) == 0) wsum[threadIdx.x >> 6] = ev;
    __syncthreads();
    if (threadIdx.x == 0) {
        int tot = 0;
        for (int k = 0; k < 16; k++) tot += wsum[k];
        events[v << 5] = tot;                // single writer per volume
    }
}

// ---------------------------------------------------------------------------
// components[v] = rootcnt[v] - events[v]
__global__ void finalize_kernel(const float* __restrict__ acc,
                                const int* __restrict__ rootcnt,
                                const int* __restrict__ events,
                                float* __restrict__ out) {
    float focal = acc[0] / (float)NEL;
    float c[NVOL];
    for (int v = 0; v < NVOL; v++)
        c[v] = (float)(rootcnt[v << 5] - events[v << 5]);
    float dp0 = 0.5f * (c[0] + c[2]);
    float dp1 = 0.5f * (c[1] + c[3]);
    float dt0 = 0.5f * (c[4] + c[6]);
    float dt1 = 0.5f * (c[5] + c[7]);
    float topo = 0.5f * (fabsf(dp0 - dt0) + fabsf(dp1 - dt1));
    out[0] = focal + 0.1f * topo;
}

// ---------------------------------------------------------------------------
extern "C" void kernel_launch(void* const* d_in, const int* in_sizes, int n_in,
                              void* d_out, int out_size, void* d_ws, size_t ws_size,
                              hipStream_t stream) {
    const float* pred = (const float*)d_in[0];
    const float* targ = (const float*)d_in[1];
    float* out = (float*)d_out;

    // header (4 KB, zeroed; per-volume counters strided to 128 B)
    float* acc     = (float*)((char*)d_ws + WS_ACC);
    int*   rootcnt = (int*)((char*)d_ws + WS_ROOT);
    int*   events  = (int*)((char*)d_ws + WS_EVT);
    int*   pcnt    = (int*)((char*)d_ws + WS_PCNT);
    unsigned short* faces = (unsigned short*)((char*)d_ws + WS_HDR);

    size_t per_vol = (size_t)FACES_PER_VOL * 2
                   + (size_t)NPLANES * SEGCAP * 4
                   + (size_t)FALLR * 4;
    size_t avail   = (ws_size > WS_HDR) ? ws_size - WS_HDR : 0;
    int vols_per_pass = (int)(avail / per_vol);
    if (vols_per_pass > NVOL) vols_per_pass = NVOL;
    if (vols_per_pass < 1) vols_per_pass = 1;
    unsigned* pairs = (unsigned*)(faces + (size_t)vols_per_pass * FACES_PER_VOL);
    int* gfall = (int*)(pairs + (size_t)vols_per_pass * NPLANES * SEGCAP);

    hipMemsetAsync(d_ws, 0, WS_HDR, stream);

    for (int vbase = 0; vbase < NVOL; vbase += vols_per_pass) {
        int nv = NVOL - vbase;
        if (nv > vols_per_pass) nv = vols_per_pass;
        dim3 tgrid(TILES_W * TILES_H, nv);
        ccl_local<<<tgrid, dim3(256), 0, stream>>>(pred, targ, faces,
                                                   rootcnt, acc, vbase);
        dim3 pgrid(NPLANES, nv);
        ccl_pairs<<<pgrid, dim3(256), 0, stream>>>(faces, pairs, pcnt, vbase);
        ccl_union<<<dim3(nv), dim3(1024), 0, stream>>>(pairs, gfall, rootcnt,
                                                       pcnt, events, vbase);
    }

    finalize_kernel<<<1, 1, 0, stream>>>(acc, rootcnt, events, out);
}

// Round 8
// 162.126 us; speedup vs baseline: 1.1828x; 1.1828x over previous
//
#include <hip/hip_runtime.h>
#include <math.h>

#define N_VOX (96*96*96)        // 884736 voxels per volume
#define NVOL 8                  // 4 pred + 4 target volumes
#define NEL (4*N_VOX)           // 3538944 elements in pred/target
#define PLANE (96*96)           // 9216

// tile geometry for local CCL: full d-span x TW x TH (TH=8: round-7 lesson --
// duration is proportional to TOTAL work, not per-block latency; TH=4 only
// added face/plane work. Throughput fix is run-space CCL, not more blocks.)
#define TW 8
#define TH 8
#define TILES_W 12
#define TILES_H 12
#define TILE_VOX (96*TW*TH)     // 6144
#define TILE_WORDS (TILE_VOX/32) // 192
#define MAXRUNS 3072            // max d-runs per tile (64 lines x 48)

#define NBPLANES 11             // interior tile boundaries per axis
#define NPAIRS (2*NBPLANES)     // 22 boundary plane-pairs per volume
#define FACES_PER_VOL (2*NPAIRS*PLANE) // 405504 ushorts
#define MAXR 40192              // dense roots that fit in 157 KB LDS
#define FALLR 65536             // global fallback capacity (ushort ID space)
#define SEGCAP 4608             // hard bound: <=48 starts/line * 96 lines/plane
#define HT2N 4096               // per-plane dedup hash entries (16 KB LDS)
#define MAX_PROBES 16

// workspace header layout (4 KB, zeroed once). Per-volume counters strided
// to 128 B (round-4 lesson: same-line cross-XCD atomics serialize ~5ns each).
#define WS_ACC   0
#define WS_ROOT  256            // int, volume v at int-index (v<<5)
#define WS_EVT   1536           // int, volume v at int-index (v<<5)
#define WS_PCNT  2816           // int [v*NPAIRS + f], single writer each
#define WS_HDR   4096

// ---------------------------------------------------------------------------
// generic-pointer union-find (works on LDS or global array). Labels only
// decrease (atomicMin) -> monotone, no cycles.
__device__ __forceinline__ int uf_find(int* __restrict__ L, int x) {
    int r = x;
    int p = L[r];
    while (p != r) { r = p; p = L[r]; }
    if (r != x) atomicMin(&L[x], r);     // path compression (monotone-safe)
    return r;
}

// returns # destroyed self-loops (exact union events).
__device__ __forceinline__ int uf_merge(int* __restrict__ L, int l1, int l2) {
    int ev = 0;
    while (l1 != l2) {
        if (l1 < l2) { int t = l1; l1 = l2; l2 = t; }   // l1 > l2
        int l3 = atomicMin(&L[l1], l2);
        if (l3 == l1) { ev++; l1 = l2; }
        else l1 = l3;
    }
    return ev;
}

// merge on LDS run labels
__device__ __forceinline__ void merge_local(int* lab, int l1, int l2) {
    while (l1 != l2 && l1 != lab[l1]) l1 = lab[l1];
    while (l1 != l2 && l2 != lab[l2]) l2 = lab[l2];
    while (l1 != l2) {
        if (l1 < l2) { int t = l1; l1 = l2; l2 = t; }
        int l3 = atomicMin(&lab[l1], l2);
        l1 = (l3 == l1) ? l2 : l3;
    }
}

// run ID (0-based, tile-global) of the run containing fg voxel i:
// rank = (#run-starts at positions <= i) - 1. Lines are word-aligned
// (96 = 3x32) so a global word-ordered prefix is line-consistent.
__device__ __forceinline__ int rrank(const unsigned* __restrict__ sm,
                                     const int* __restrict__ wpf, int i) {
    int w = i >> 5, b = i & 31;
    unsigned mask = (2u << b) - 1u;      // bits 0..b inclusive (b=31 -> all)
    return wpf[w] + __popc(sm[w] & mask) - 1;
}

// ---------------------------------------------------------------------------
// Phase 1: RUN-SPACE per-tile CCL in LDS (round-7 rewrite). fm bitmask ->
// start-masks sm[] + prefix wpf[] give O(1) voxel->runID rank; union-find
// runs over <=3072 run slots (14.6 KB LDS total, 8 blocks/CU). Roots get
// DENSE per-volume IDs. Outputs ONLY ushort face arrays + rootcnt + focal.
__global__ __launch_bounds__(256) void ccl_local(const float* __restrict__ pred,
                                                 const float* __restrict__ targ,
                                                 unsigned short* __restrict__ faces,
                                                 int* __restrict__ rootcnt,
                                                 float* __restrict__ acc,
                                                 int vbase) {
    __shared__ int      lab[MAXRUNS];        // 12 KB run union-find
    __shared__ unsigned fm[TILE_WORDS];      // 768 B fg bits
    __shared__ unsigned sm[TILE_WORDS];      // 768 B run-start bits
    __shared__ int      wpf[TILE_WORDS];     // 768 B exclusive start prefix
    __shared__ float fws[4];
    __shared__ int   iws[4];
    __shared__ int   gbase;

    int vloc = blockIdx.y;
    int v = vbase + vloc;
    int tile = blockIdx.x;                   // 0..143
    int tw = tile % TILES_W, th = tile / TILES_W;
    int w0 = tw * TW, h0 = th * TH;
    int tbase = h0 * PLANE + w0 * 96;        // global index of tile origin
    unsigned short* Fw = faces + (size_t)vloc * FACES_PER_VOL;  // [b][side][h*96+d]
    unsigned short* Fh = Fw + 2 * NBPLANES * PLANE;             // [b][side][w*96+d]

    // ---- load: fg bits via ballot; fast focal partial for pred volumes ----
    float fsum = 0.0f;
    for (int it = 0; it < TILE_VOX / 256; it++) {
        int i = it * 256 + threadIdx.x;
        int lh = i / 768;                    // i = lh*768 + lw*96 + d
        int j = tbase + i + lh * 8448;       // global voxel index
        bool f;
        if (v < 4) {
            float xv = pred[(size_t)v * N_VOX + j];
            float tv = targ[(size_t)v * N_VOX + j];
            f = xv > 0.0f;                   // sigmoid(x)>0.5 <=> x>0
            float m   = (tv == 1.0f) ? -xv : xv;
            float at  = (tv == 1.0f) ? 0.25f : 0.75f;
            float e   = __expf(-fabsf(m));
            float inv = 1.0f / (1.0f + e);
            float sig = inv * ((m >= 0.0f) ? 1.0f : e);    // sigmoid(m)
            float sp  = fmaxf(m, 0.0f) + __logf(1.0f + e); // softplus(m)
            fsum += at * sig * sig * sp;
        } else {
            f = targ[(size_t)(v - 4) * N_VOX + j] > 0.5f;
        }
        unsigned long long bal = __ballot(f);
        if ((threadIdx.x & 63) == 0) {
            fm[i >> 5]       = (unsigned)bal;
            fm[(i >> 5) + 1] = (unsigned)(bal >> 32);
        }
    }
    __syncthreads();

    // ---- A: start masks + block scan -> run ranks; init run labels ----
    int cnt = 0;
    {
        unsigned st = 0;
        if (threadIdx.x < TILE_WORDS) {
            unsigned m = fm[threadIdx.x];
            unsigned carry = (threadIdx.x % 3) ? (fm[threadIdx.x - 1] >> 31) : 0u;
            st = m & ~((m << 1) | carry);
            sm[threadIdx.x] = st;
            cnt = __popc(st);
        }
    }
    int inc = cnt;
    for (int off = 1; off < 64; off <<= 1) {
        int u = __shfl_up(inc, off, 64);
        if ((threadIdx.x & 63) >= off) inc += u;
    }
    int wid = threadIdx.x >> 6;
    if ((threadIdx.x & 63) == 63) iws[wid] = inc;
    for (int r = threadIdx.x; r < MAXRUNS; r += 256) lab[r] = r;
    __syncthreads();
    int woff = 0;
    for (int k = 0; k < wid; k++) woff += iws[k];
    if (threadIdx.x < TILE_WORDS) wpf[threadIdx.x] = woff + inc - cnt;
    int Nr = iws[0] + iws[1] + iws[2];       // total runs (wave 3 adds none)
    __syncthreads();

    // ---- B: merge overlap-segment starts, w then h direction ----
    for (int t = threadIdx.x; t < 336; t += 256) {
        bool wdirn = t < 168;
        int tt = wdirn ? t : t - 168;
        int lh, lw, k;
        if (wdirn) { lh = tt / 21; int rem = tt % 21; lw = rem / 3; k = rem % 3; }
        else       { lh = tt / 24; int rem = tt % 24; lw = rem / 3; k = rem % 3; }
        int wb = (lh * 8 + lw) * 3 + k;
        int nb = wb + (wdirn ? 3 : 24);
        unsigned ov = fm[wb] & fm[nb];
        if (!ov) continue;
        unsigned carry = (k > 0) ? ((fm[wb - 1] & fm[nb - 1]) >> 31) : 0u;
        unsigned starts = ov & ~((ov << 1) | carry);
        int base_i = wb << 5;
        int dir = wdirn ? 96 : 768;
        while (starts) {
            int b = __builtin_ctz(starts);
            starts &= starts - 1;
            int i = base_i + b;
            merge_local(lab, rrank(sm, wpf, i), rrank(sm, wpf, i + dir));
        }
    }
    __syncthreads();

    // ---- C: count roots, dense-ID assign (full-lane strided run loops) ----
    int myroots = 0;
    for (int r = threadIdx.x; r < Nr; r += 256)
        if (lab[r] == r) myroots++;
    int s = myroots;
    for (int off = 1; off < 64; off <<= 1) {
        int u = __shfl_up(s, off, 64);
        if ((threadIdx.x & 63) >= off) s += u;
    }
    if ((threadIdx.x & 63) == 63) iws[wid] = s;
    __syncthreads();
    int wbase = 0;
    for (int k = 0; k < wid; k++) wbase += iws[k];
    if (threadIdx.x == 0)
        gbase = atomicAdd(&rootcnt[v << 5], iws[0] + iws[1] + iws[2] + iws[3]);
    __syncthreads();
    int nid = gbase + wbase + (s - myroots);
    for (int r = threadIdx.x; r < Nr; r += 256)
        if (lab[r] == r) lab[r] = ~(nid++);   // same iteration order as count
    __syncthreads();

    // ---- D: flatten non-roots to ~denseID (monotone, race-safe) ----
    for (int r = threadIdx.x; r < Nr; r += 256) {
        int p = lab[r];
        if (p >= 0) {
            int q2 = lab[p];
            while (q2 >= 0) { p = q2; q2 = lab[p]; }
            lab[r] = q2;
        }
    }
    __syncthreads();

    // ---- E: resolve + store the 4 interior-adjacent faces (ushort4) ----
    for (int t = threadIdx.x; t < 768; t += 256) {
        int f  = t / 192;
        int g  = t % 192;
        int u  = g / 24;                     // row within face (lh or lw)
        int d4 = (g % 24) * 4;
        int i0; unsigned short* dst;
        if (f == 0) {
            if (tw == 0) continue;
            i0  = u * 768 + d4;
            dst = Fw + ((tw - 1) * 2 + 1) * PLANE + (h0 + u) * 96 + d4;
        } else if (f == 1) {
            if (tw == TILES_W - 1) continue;
            i0  = u * 768 + 7 * 96 + d4;
            dst = Fw + (tw * 2) * PLANE + (h0 + u) * 96 + d4;
        } else if (f == 2) {
            if (th == 0) continue;
            i0  = u * 96 + d4;
            dst = Fh + ((th - 1) * 2 + 1) * PLANE + (w0 + u) * 96 + d4;
        } else {
            if (th == TILES_H - 1) continue;
            i0  = 7 * 768 + u * 96 + d4;
            dst = Fh + (th * 2) * PLANE + (w0 + u) * 96 + d4;
        }
        unsigned mw = fm[i0 >> 5];           // bits d4..d4+3 in one word
        unsigned short vals[4];
        bool prevf = false;
        for (int q = 0; q < 4; q++) {
            bool fb = (mw >> ((d4 & 31) + q)) & 1;
            if (fb) vals[q] = prevf ? vals[q - 1]
                                    : (unsigned short)(~lab[rrank(sm, wpf, i0 + q)]);
            else vals[q] = 0xFFFFu;
            prevf = fb;
        }
        *(ushort4*)dst = make_ushort4(vals[0], vals[1], vals[2], vals[3]);
    }

    // ---- wave-shuffle reduction: focal partial ----
    for (int off = 32; off; off >>= 1) fsum += __shfl_down(fsum, off, 64);
    if ((threadIdx.x & 63) == 0) fws[wid] = fsum;
    __syncthreads();
    if (threadIdx.x == 0) {
        float ft = fws[0] + fws[1] + fws[2] + fws[3];
        if (v < 4 && ft != 0.0f) atomicAdd(acc, ft);
    }
}

// ---------------------------------------------------------------------------
// Phase 2a: WIDE pair extraction + dedup. One block per (plane-pair, volume).
// Streams its 2x9216-ushort plane coalesced, extracts overlap-segment-start
// (a,b) pairs, dedups via a private 16 KB LDS hash, writes uniques to its
// PRIVATE global segment indexed by an LDS counter -- zero global atomics
// (round-4 lesson). Probe-cap dupes kept (harmless downstream).
__global__ __launch_bounds__(256) void ccl_pairs(const unsigned short* __restrict__ faces,
                                                 unsigned* __restrict__ pairs,
                                                 int* __restrict__ pcnt,
                                                 int vbase) {
    __shared__ unsigned ht[HT2N];            // 16 KB
    __shared__ int nloc;
    for (int i = threadIdx.x; i < HT2N; i += 256) ht[i] = 0xFFFFFFFFu;
    if (threadIdx.x == 0) nloc = 0;
    __syncthreads();

    int f    = blockIdx.x;                   // plane pair 0..21
    int vloc = blockIdx.y;
    int v    = vbase + vloc;
    const unsigned short* A = faces + (size_t)vloc * FACES_PER_VOL
                                    + (size_t)(2 * f) * PLANE;
    const unsigned short* B = A + PLANE;
    unsigned* pb = pairs + ((size_t)vloc * NPAIRS + f) * SEGCAP;

    const int GPP = PLANE / 8;               // 1152 8-wide groups
    for (int g = threadIdx.x; g < GPP; g += 256) {
        int e8 = g * 8;
        int4 aw = *(const int4*)(A + e8);    // 8 ushorts, coalesced 16B
        int4 bw = *(const int4*)(B + e8);
        unsigned a32[4] = {(unsigned)aw.x, (unsigned)aw.y, (unsigned)aw.z, (unsigned)aw.w};
        unsigned b32[4] = {(unsigned)bw.x, (unsigned)bw.y, (unsigned)bw.z, (unsigned)bw.w};
        bool pf = false;
        if (e8 % 96) pf = (A[e8 - 1] != 0xFFFFu) && (B[e8 - 1] != 0xFFFFu);
        #pragma unroll
        for (int q = 0; q < 8; q++) {
            unsigned av = (a32[q >> 1] >> ((q & 1) * 16)) & 0xFFFFu;
            unsigned bv = (b32[q >> 1] >> ((q & 1) * 16)) & 0xFFFFu;
            bool f2 = (av != 0xFFFFu) && (bv != 0xFFFFu);
            if (f2 && !pf && av != bv) {     // overlap-segment start along d
                unsigned lo = av < bv ? av : bv;
                unsigned hi = av < bv ? bv : av;
                unsigned key = (lo << 16) | hi;
                unsigned h = (key * 2654435761u) >> 20;   // -> 12-bit slot
                bool fresh = false;
                for (int pr = 0; pr < MAX_PROBES; pr++) {
                    unsigned prev = atomicCAS(&ht[h], 0xFFFFFFFFu, key);
                    if (prev == 0xFFFFFFFFu) { fresh = true; break; }
                    if (prev == key) break;
                    h = (h + 1) & (HT2N - 1);
                    if (pr == MAX_PROBES - 1) fresh = true;  // cap: keep dupe
                }
                if (fresh) {
                    int ix = atomicAdd(&nloc, 1);    // LDS atomic, on-CU
                    pb[ix] = key;                    // ix < SEGCAP bound
                }
            }
            pf = f2;
        }
    }
    __syncthreads();
    if (threadIdx.x == 0) pcnt[v * NPAIRS + f] = nloc;   // single writer
}

// ---------------------------------------------------------------------------
// Phase 2b: NARROW exact union-find. One 1024-thread block per volume over
// the dense root ID space in 157 KB LDS; walks the 22 per-plane unique-pair
// segments. components = roots - events (destroyed self-loops).
__global__ __launch_bounds__(1024) void ccl_union(const unsigned* __restrict__ pairs,
                                                  int* __restrict__ gfall,
                                                  const int* __restrict__ rootcnt,
                                                  const int* __restrict__ pcnt,
                                                  int* __restrict__ events,
                                                  int vbase) {
    __shared__ int slab[MAXR];               // 157 KB dense union-find
    __shared__ int wsum[16];
    int vloc = blockIdx.x;
    int v = vbase + vloc;
    int R  = rootcnt[v << 5];

    int* lab = (R <= MAXR) ? (int*)slab : (gfall + (size_t)vloc * FALLR);
    for (int i = threadIdx.x; i < R; i += 1024) lab[i] = i;
    __syncthreads();

    int ev = 0;
    for (int f = 0; f < NPAIRS; f++) {
        int np = pcnt[v * NPAIRS + f];
        const unsigned* pb = pairs + ((size_t)vloc * NPAIRS + f) * SEGCAP;
        for (int i = threadIdx.x; i < np; i += 1024) {
            unsigned key = pb[i];
            int a = (int)(key >> 16), b = (int)(key & 0xFFFFu);
            int ra = uf_find(lab, a);
            int rb = uf_find(lab, b);
            if (ra != rb) ev += uf_merge(lab, ra, rb);
        }
    }

    // block reduction of union events
    for (int off = 32; off; off >>= 1) ev += __shfl_down(ev, off, 64);
    if ((threadIdx.x & 63) == 0) wsum[threadIdx.x >> 6] = ev;
    __syncthreads();
    if (threadIdx.x == 0) {
        int tot = 0;
        for (int k = 0; k < 16; k++) tot += wsum[k];
        events[v << 5] = tot;                // single writer per volume
    }
}

// ---------------------------------------------------------------------------
// components[v] = rootcnt[v] - events[v]
__global__ void finalize_kernel(const float* __restrict__ acc,
                                const int* __restrict__ rootcnt,
                                const int* __restrict__ events,
                                float* __restrict__ out) {
    float focal = acc[0] / (float)NEL;
    float c[NVOL];
    for (int v = 0; v < NVOL; v++)
        c[v] = (float)(rootcnt[v << 5] - events[v << 5]);
    float dp0 = 0.5f * (c[0] + c[2]);
    float dp1 = 0.5f * (c[1] + c[3]);
    float dt0 = 0.5f * (c[4] + c[6]);
    float dt1 = 0.5f * (c[5] + c[7]);
    float topo = 0.5f * (fabsf(dp0 - dt0) + fabsf(dp1 - dt1));
    out[0] = focal + 0.1f * topo;
}

// ---------------------------------------------------------------------------
extern "C" void kernel_launch(void* const* d_in, const int* in_sizes, int n_in,
                              void* d_out, int out_size, void* d_ws, size_t ws_size,
                              hipStream_t stream) {
    const float* pred = (const float*)d_in[0];
    const float* targ = (const float*)d_in[1];
    float* out = (float*)d_out;

    // header (4 KB, zeroed; per-volume counters strided to 128 B)
    float* acc     = (float*)((char*)d_ws + WS_ACC);
    int*   rootcnt = (int*)((char*)d_ws + WS_ROOT);
    int*   events  = (int*)((char*)d_ws + WS_EVT);
    int*   pcnt    = (int*)((char*)d_ws + WS_PCNT);
    unsigned short* faces = (unsigned short*)((char*)d_ws + WS_HDR);

    size_t per_vol = (size_t)FACES_PER_VOL * 2
                   + (size_t)NPAIRS * SEGCAP * 4
                   + (size_t)FALLR * 4;
    size_t avail   = (ws_size > WS_HDR) ? ws_size - WS_HDR : 0;
    int vols_per_pass = (int)(avail / per_vol);
    if (vols_per_pass > NVOL) vols_per_pass = NVOL;
    if (vols_per_pass < 1) vols_per_pass = 1;
    unsigned* pairs = (unsigned*)(faces + (size_t)vols_per_pass * FACES_PER_VOL);
    int* gfall = (int*)(pairs + (size_t)vols_per_pass * NPAIRS * SEGCAP);

    hipMemsetAsync(d_ws, 0, WS_HDR, stream);

    for (int vbase = 0; vbase < NVOL; vbase += vols_per_pass) {
        int nv = NVOL - vbase;
        if (nv > vols_per_pass) nv = vols_per_pass;
        dim3 tgrid(TILES_W * TILES_H, nv);
        ccl_local<<<tgrid, dim3(256), 0, stream>>>(pred, targ, faces,
                                                   rootcnt, acc, vbase);
        dim3 pgrid(NPAIRS, nv);
        ccl_pairs<<<pgrid, dim3(256), 0, stream>>>(faces, pairs, pcnt, vbase);
        ccl_union<<<dim3(nv), dim3(1024), 0, stream>>>(pairs, gfall, rootcnt,
                                                       pcnt, events, vbase);
    }

    finalize_kernel<<<1, 1, 0, stream>>>(acc, rootcnt, events, out);
}